// Round 16
// baseline (55.478 us; speedup 1.0000x reference)
//
#include <hip/hip_runtime.h>

typedef short  bf16x8 __attribute__((ext_vector_type(8)));
typedef float  f32x4  __attribute__((ext_vector_type(4)));

#define WROWS 22            // 16 output rows + 6 halo
#define WSTR  72            // ushorts per row (144 B, 16B-multiple)
#define WPAD  8             // lane63/jo3 b128 overrun: must be zeroed, finite
#define WSZ   (WROWS * WSTR + WPAD)   // 1592 ushorts = 3184 B (16B-aligned)
#define NCHW  18            // float4 chunks per row
#define CHTW  (WROWS * NCHW)          // 396 chunks per wave-tile
#define NTILE 4             // x-adjacent tiles per wave

static __device__ __forceinline__ unsigned int rne16(float f) {
    unsigned int u = __float_as_uint(f);
    return (u + 0x7FFFu + ((u >> 16) & 1u)) >> 16;   // fp32 -> bf16 RNE
}

// ---- Setup: banded-B fragments once into ws (7 dy x 64 lanes x 16B) ----
// B[u][j] = w[dy][u-j-1]; rows u >= 23 structurally zero (kills A-read wrap).
__global__ void build_bfrag(const float* __restrict__ w, bf16x8* __restrict__ ws) {
    const int l   = threadIdx.x;      // 64 threads
    const int l15 = l & 15;
    const int u0  = (l >> 4) * 8;
#pragma unroll
    for (int dy = 0; dy < 7; ++dy) {
        union { unsigned int u[4]; bf16x8 v; } bb;
#pragma unroll
        for (int qp = 0; qp < 4; ++qp) {
            unsigned int half[2];
#pragma unroll
            for (int h = 0; h < 2; ++h) {
                const int d = u0 + qp * 2 + h - l15 - 1;     // weight col dx
                const float val = (d >= 0 && d < 7) ? w[dy * 7 + d] : 0.f;
                half[h] = rne16(val);
            }
            bb.u[qp] = half[0] | (half[1] << 16);
        }
        ws[dy * 64 + l] = bb.v;
    }
}

// ---- Main: barrier-free, wave-private LDS, 4-tile within-wave pipeline.
// No __syncthreads anywhere -> hipcc emits COUNTED vmcnt in straight-line
// code: tile k+1's loads stay in flight across ldswrite(k)+compute(k). ----
__global__ __launch_bounds__(256)
void conv7x7_mfma(const float* __restrict__ x, const bf16x8* __restrict__ Bws,
                  float* __restrict__ out) {
    __shared__ unsigned short lds[4][2][WSZ];   // 25472 B/block -> 6 blocks/CU

    const int W = 512, H = 512;
    // XCD-aware bijective swizzle (2048 % 8 == 0)
    const int raw = blockIdx.x;
    const int bi  = (raw & 7) * 256 + (raw >> 3);
    const int n   = bi >> 4;             // n(7) | ty(3) | g(1)
    const int ty  = (bi >> 1) & 7;
    const int g   = bi & 1;

    const float* xn = x + (size_t)n * (H * W);
    float*       on = out + (size_t)n * (H * W);

    const int t   = threadIdx.x;
    const int l   = t & 63;
    const int wv  = t >> 6;
    const int l15 = l & 15;
    const int lk  = l >> 4;
    const int u0  = lk * 8;

    const int y0  = ty * 64 + wv * 16;   // wave's output rows y0..y0+15
    const int x0g = g * 256;             // tiles at x0g + 64k, k=0..3

    // Zero both pads (wave-private; read-only wrap region)
    if (l < WPAD) { lds[wv][0][WROWS * WSTR + l] = 0; lds[wv][1][WROWS * WSTR + l] = 0; }

    // Prebuilt B fragments (L2-resident broadcast)
    bf16x8 Bf[7];
#pragma unroll
    for (int dy = 0; dy < 7; ++dy) Bf[dy] = Bws[dy * 64 + l];

    // k-invariant staging descriptors (7 chunks/lane per tile)
    int  d_roff[7], d_loff[7], d_xoff[7];
    bool d_rok[7], d_act[7];
#pragma unroll
    for (int it = 0; it < 7; ++it) {
        const int idx = l + 64 * it;
        const int r   = idx / NCHW;
        const int cc  = idx - r * NCHW;
        const int gr  = y0 - 3 + r;
        d_act[it]  = (idx < CHTW);
        d_rok[it]  = d_act[it] && (gr >= 0) && (gr < H);
        d_xoff[it] = x0g - 4 + 4 * cc;
        d_roff[it] = gr * W;
        d_loff[it] = r * WSTR + 4 * cc;
    }

    float4 sregA[7], sregB[7];

#define ISSUE(SR, k_)                                                          \
    {                                                                          \
        _Pragma("unroll")                                                      \
        for (int it = 0; it < 7; ++it) {                                       \
            const int gc = d_xoff[it] + 64 * (k_);                             \
            float4 v = make_float4(0.f, 0.f, 0.f, 0.f);                        \
            if (d_rok[it] && gc >= 0 && gc <= W - 4)                           \
                v = *reinterpret_cast<const float4*>(&xn[d_roff[it] + gc]);    \
            SR[it] = v;                                                        \
        }                                                                      \
    }

#define LDSWRITE(SR, buf_)                                                     \
    {                                                                          \
        _Pragma("unroll")                                                      \
        for (int it = 0; it < 7; ++it) {                                       \
            if (d_act[it]) {                                                   \
                const unsigned p0 = rne16(SR[it].x) | (rne16(SR[it].y) << 16); \
                const unsigned p1 = rne16(SR[it].z) | (rne16(SR[it].w) << 16); \
                *reinterpret_cast<uint2*>(&lds[wv][buf_][d_loff[it]]) =        \
                    make_uint2(p0, p1);                                        \
            }                                                                  \
        }                                                                      \
    }

#define COMPUTE(k_, buf_)                                                      \
    {                                                                          \
        const int xk = x0g + 64 * (k_);                                        \
        _Pragma("unroll")                                                      \
        for (int jo = 0; jo < 4; ++jo) {                                       \
            f32x4 acc = {0.f, 0.f, 0.f, 0.f};                                  \
            _Pragma("unroll")                                                  \
            for (int dy = 0; dy < 7; ++dy) {                                   \
                const int row = l15 + dy;                                      \
                const bf16x8 a = *reinterpret_cast<const bf16x8*>(             \
                    &lds[wv][buf_][row * WSTR + jo * 16 + u0]);                \
                acc = __builtin_amdgcn_mfma_f32_16x16x32_bf16(a, Bf[dy], acc,  \
                                                              0, 0, 0);        \
            }                                                                  \
            _Pragma("unroll")                                                  \
            for (int rr = 0; rr < 4; ++rr) {                                   \
                const int gr = y0 + lk * 4 + rr;                               \
                on[(size_t)gr * W + xk + jo * 16 + l15] = acc[rr];             \
            }                                                                  \
        }                                                                      \
    }

    // Within-wave pipeline: issue(k+1) before ldswrite(k)'s wait.
    // Buffer reuse (e.g. buf0: compute(0) reads, ldswrite(2) writes) is
    // same-wave program order -> compiler-enforced lgkmcnt, no races.
    ISSUE(sregA, 0)
    ISSUE(sregB, 1)
    LDSWRITE(sregA, 0)         // waits only sregA's 7 loads (counted vmcnt)
    COMPUTE(0, 0)
    ISSUE(sregA, 2)
    LDSWRITE(sregB, 1)
    COMPUTE(1, 1)
    ISSUE(sregB, 3)
    LDSWRITE(sregA, 0)
    COMPUTE(2, 0)
    LDSWRITE(sregB, 1)
    COMPUTE(3, 1)

#undef ISSUE
#undef LDSWRITE
#undef COMPUTE
}

extern "C" void kernel_launch(void* const* d_in, const int* in_sizes, int n_in,
                              void* d_out, int out_size, void* d_ws, size_t ws_size,
                              hipStream_t stream) {
    const float* x = (const float*)d_in[0];
    const float* w = (const float*)d_in[1];
    float* out = (float*)d_out;
    bf16x8* bws = (bf16x8*)d_ws;

    build_bfrag<<<1, 64, 0, stream>>>(w, bws);

    const int nblocks = 128 * 8 * 2;   // 2048 blocks x 256 threads (4 waves)
    conv7x7_mfma<<<nblocks, 256, 0, stream>>>(x, bws, out);
}

// Round 17
// 48.502 us; speedup vs baseline: 1.1438x; 1.1438x over previous
//
#include <hip/hip_runtime.h>

typedef short  bf16x8 __attribute__((ext_vector_type(8)));
typedef float  f32x4  __attribute__((ext_vector_type(4)));

#define WROWS 22            // 16 output rows + 6 halo
#define WSTR  72            // ushorts per row (144 B, 16B-multiple)
#define WPAD  8             // lane63/jo3 b128 overrun: must be zeroed, finite
#define WSZ   (WROWS * WSTR + WPAD)   // 1592 ushorts = 3184 B
#define NCHW  18            // float4 chunks per row
#define CHTW  (WROWS * NCHW)          // 396 chunks per wave-tile

static __device__ __forceinline__ unsigned int rne16(float f) {
    unsigned int u = __float_as_uint(f);
    return (u + 0x7FFFu + ((u >> 16) & 1u)) >> 16;   // fp32 -> bf16 RNE
}

// ---- Setup: banded-B fragments once into ws (7 dy x 64 lanes x 16B) ----
// B[u][j] = w[dy][u-j-1]; rows u >= 23 structurally zero (kills A-read wrap).
__global__ void build_bfrag(const float* __restrict__ w, bf16x8* __restrict__ ws) {
    const int l   = threadIdx.x;      // 64 threads
    const int l15 = l & 15;
    const int u0  = (l >> 4) * 8;
#pragma unroll
    for (int dy = 0; dy < 7; ++dy) {
        union { unsigned int u[4]; bf16x8 v; } bb;
#pragma unroll
        for (int qp = 0; qp < 4; ++qp) {
            unsigned int half[2];
#pragma unroll
            for (int h = 0; h < 2; ++h) {
                const int d = u0 + qp * 2 + h - l15 - 1;     // weight col dx
                const float val = (d >= 0 && d < 7) ? w[dy * 7 + d] : 0.f;
                half[h] = rne16(val);
            }
            bb.u[qp] = half[0] | (half[1] << 16);
        }
        ws[dy * 64 + l] = bb.v;
    }
}

// ---- Main: barrier-free wave-private LDS (R15 footprint), 2 tiles/wave
// pipelined through ONE buffer: issue both tiles' loads up front; counted
// vmcnt (no barriers) lets tile-1 loads fly over ldswrite(0)+compute(0). ----
__global__ __launch_bounds__(256)
void conv7x7_mfma(const float* __restrict__ x, const bf16x8* __restrict__ Bws,
                  float* __restrict__ out) {
    __shared__ unsigned short lds[4][WSZ];   // 12736 B/block (= R15)

    const int W = 512, H = 512;
    // XCD-aware bijective swizzle (4096 % 8 == 0)
    const int raw = blockIdx.x;
    const int bi  = (raw & 7) * 512 + (raw >> 3);
    const int n   = bi >> 5;             // n(7) | ty(3) | gx(2)
    const int ty  = (bi >> 2) & 7;
    const int gx  = bi & 3;

    const float* xn = x + (size_t)n * (H * W);
    float*       on = out + (size_t)n * (H * W);

    const int t   = threadIdx.x;
    const int l   = t & 63;
    const int wv  = t >> 6;
    const int l15 = l & 15;
    const int lk  = l >> 4;
    const int u0  = lk * 8;

    const int y0  = ty * 64 + wv * 16;   // wave's output rows y0..y0+15
    const int x0g = gx * 128;            // two tiles: x0g, x0g+64

    unsigned short* my = lds[wv];        // wave-private region

    // Zero the pad (wave-private read-only wrap region)
    if (l < WPAD) my[WROWS * WSTR + l] = 0;

    // Prebuilt B fragments (L2-resident broadcast)
    bf16x8 Bf[7];
#pragma unroll
    for (int dy = 0; dy < 7; ++dy) Bf[dy] = Bws[dy * 64 + l];

    // k-invariant staging descriptors (7 chunks/lane per tile)
    int  d_roff[7], d_loff[7], d_xoff[7];
    bool d_rok[7], d_act[7];
#pragma unroll
    for (int it = 0; it < 7; ++it) {
        const int idx = l + 64 * it;
        const int r   = idx / NCHW;
        const int cc  = idx - r * NCHW;
        const int gr  = y0 - 3 + r;
        d_act[it]  = (idx < CHTW);
        d_rok[it]  = d_act[it] && (gr >= 0) && (gr < H);
        d_xoff[it] = x0g - 4 + 4 * cc;
        d_roff[it] = gr * W;
        d_loff[it] = r * WSTR + 4 * cc;
    }

    float4 sregA[7], sregB[7];

#define ISSUE(SR, k_)                                                          \
    {                                                                          \
        _Pragma("unroll")                                                      \
        for (int it = 0; it < 7; ++it) {                                       \
            const int gc = d_xoff[it] + 64 * (k_);                             \
            float4 v = make_float4(0.f, 0.f, 0.f, 0.f);                        \
            if (d_rok[it] && gc >= 0 && gc <= W - 4)                           \
                v = *reinterpret_cast<const float4*>(&xn[d_roff[it] + gc]);    \
            SR[it] = v;                                                        \
        }                                                                      \
    }

#define LDSWRITE(SR)                                                           \
    {                                                                          \
        _Pragma("unroll")                                                      \
        for (int it = 0; it < 7; ++it) {                                       \
            if (d_act[it]) {                                                   \
                const unsigned p0 = rne16(SR[it].x) | (rne16(SR[it].y) << 16); \
                const unsigned p1 = rne16(SR[it].z) | (rne16(SR[it].w) << 16); \
                *reinterpret_cast<uint2*>(&my[d_loff[it]]) =                   \
                    make_uint2(p0, p1);                                        \
            }                                                                  \
        }                                                                      \
    }

#define COMPUTE(k_)                                                            \
    {                                                                          \
        const int xk = x0g + 64 * (k_);                                        \
        _Pragma("unroll")                                                      \
        for (int jo = 0; jo < 4; ++jo) {                                       \
            f32x4 acc = {0.f, 0.f, 0.f, 0.f};                                  \
            _Pragma("unroll")                                                  \
            for (int dy = 0; dy < 7; ++dy) {                                   \
                const int row = l15 + dy;                                      \
                const bf16x8 a = *reinterpret_cast<const bf16x8*>(             \
                    &my[row * WSTR + jo * 16 + u0]);                           \
                acc = __builtin_amdgcn_mfma_f32_16x16x32_bf16(a, Bf[dy], acc,  \
                                                              0, 0, 0);        \
            }                                                                  \
            _Pragma("unroll")                                                  \
            for (int rr = 0; rr < 4; ++rr) {                                   \
                const int gr = y0 + lk * 4 + rr;                               \
                on[(size_t)gr * W + xk + jo * 16 + l15] = acc[rr];             \
            }                                                                  \
        }                                                                      \
    }

    // Pipeline: both tiles' loads issued up front (14 in flight).
    // LDSWRITE(sregA) waits vmcnt(7) only; tile-1 loads hide under
    // write(0)+compute(0). LDSWRITE(sregB) follows compute(0)'s ds_reads
    // in same-wave program order (in-order DS) -> no race, no barrier.
    ISSUE(sregA, 0)
    ISSUE(sregB, 1)
    LDSWRITE(sregA)
    COMPUTE(0)
    LDSWRITE(sregB)
    COMPUTE(1)

#undef ISSUE
#undef LDSWRITE
#undef COMPUTE
}

extern "C" void kernel_launch(void* const* d_in, const int* in_sizes, int n_in,
                              void* d_out, int out_size, void* d_ws, size_t ws_size,
                              hipStream_t stream) {
    const float* x = (const float*)d_in[0];
    const float* w = (const float*)d_in[1];
    float* out = (float*)d_out;
    bf16x8* bws = (bf16x8*)d_ws;

    build_bfrag<<<1, 64, 0, stream>>>(w, bws);

    const int nblocks = 128 * 8 * 4;   // 4096 blocks x 256 threads (4 waves)
    conv7x7_mfma<<<nblocks, 256, 0, stream>>>(x, bws, out);
}